// Round 5
// baseline (567.334 us; speedup 1.0000x reference)
//
#include <hip/hip_runtime.h>
#include <hip/hip_bf16.h>
#include <math.h>

#define HIDC 256

typedef short short8 __attribute__((ext_vector_type(8)));
typedef float f32x4 __attribute__((ext_vector_type(4)));

__device__ __forceinline__ ushort f2bf_rne(float f) {
    uint u = __float_as_uint(f);
    u += 0x7FFF + ((u >> 16) & 1);
    return (ushort)(u >> 16);
}
__device__ __forceinline__ float bf2f(ushort h) {
    return __uint_as_float(((uint)h) << 16);
}

// pack 8 f32 -> short8 bf16 RNE (all const-indexed -> stays in registers)
__device__ __forceinline__ short8 pack8_rne(float4 a, float4 b) {
    ushort h[8];
    h[0] = f2bf_rne(a.x); h[1] = f2bf_rne(a.y); h[2] = f2bf_rne(a.z); h[3] = f2bf_rne(a.w);
    h[4] = f2bf_rne(b.x); h[5] = f2bf_rne(b.y); h[6] = f2bf_rne(b.z); h[7] = f2bf_rne(b.w);
    return *(short8*)h;
}
// split 8 f32 into hi (truncated bf16) + lo (RNE of residual) -- identical to old staged split
__device__ __forceinline__ void split8(float4 a, float4 b, short8& hi, short8& lo) {
    float v[8] = {a.x, a.y, a.z, a.w, b.x, b.y, b.z, b.w};
    ushort hh[8], ll[8];
#pragma unroll
    for (int q = 0; q < 8; q++) {
        uint u = __float_as_uint(v[q]);
        hh[q] = (ushort)(u >> 16);
        ll[q] = f2bf_rne(v[q] - __uint_as_float(u & 0xFFFF0000u));
    }
    hi = *(short8*)hh; lo = *(short8*)ll;
}

// ---------------- small utility kernels ----------------

__global__ void fill_i_kernel(int* __restrict__ p, int v, int n) {
    int i = blockIdx.x * 256 + threadIdx.x;
    if (i < n) p[i] = v;
}

__global__ void deg_kernel(const int* __restrict__ dst, int* __restrict__ deg, int E) {
    int e = blockIdx.x * 256 + threadIdx.x;
    if (e < E) atomicAdd(&deg[dst[e]], 1);
}

__global__ void rsqrt_kernel(const int* __restrict__ deg, float* __restrict__ dinv, int n) {
    int i = blockIdx.x * 256 + threadIdx.x;
    if (i < n) dinv[i] = rsqrtf((float)(deg[i] + 1));   // +1 = self-loop
}

// ---------------- 3-kernel exclusive scan ----------------

__device__ __forceinline__ int block_incl_scan(int v, int tid) {
#pragma unroll
    for (int off = 1; off < 64; off <<= 1) {
        int t = __shfl_up(v, off);
        if ((tid & 63) >= off) v += t;
    }
    __shared__ int wt[4];
    if ((tid & 63) == 63) wt[tid >> 6] = v;
    __syncthreads();
    int wid = tid >> 6;
    for (int w = 0; w < wid; w++) v += wt[w];
    __syncthreads();
    return v;
}

__global__ void scan_a_kernel(const int* __restrict__ deg, int* __restrict__ row_start,
                              int* __restrict__ blocksum, int N) {
    int tid = threadIdx.x;
    int i = blockIdx.x * 256 + tid;
    int v = (i < N) ? deg[i] : 0;
    int incl = block_incl_scan(v, tid);
    if (i < N) row_start[i + 1] = incl;
    if (tid == 255) blocksum[blockIdx.x] = incl;
}

__global__ void scan_b_kernel(int* __restrict__ blocksum, int nb) {
    int tid = threadIdx.x;
    int v = (tid < nb) ? blocksum[tid] : 0;
    int incl = block_incl_scan(v, tid);
    if (tid < nb) blocksum[tid] = incl;
}

__global__ void scan_c_kernel(int* __restrict__ row_start, int* __restrict__ cursor,
                              const int* __restrict__ blocksum, int N) {
    int b = blockIdx.x;
    int i = b * 256 + threadIdx.x;
    int add = (b > 0) ? blocksum[b - 1] : 0;
    if (i < N) {
        int v = row_start[i + 1] + add;
        row_start[i + 1] = v;
        cursor[i + 1] = v;
    }
    if (b == 0 && threadIdx.x == 0) { row_start[0] = 0; cursor[0] = 0; }
}

__global__ void scatter_kernel(const int* __restrict__ src, const int* __restrict__ dst,
                               const float* __restrict__ dinv, int* __restrict__ cursor,
                               int* __restrict__ csr_src, float* __restrict__ csr_w, int E) {
    int e = blockIdx.x * 256 + threadIdx.x;
    if (e < E) {
        int s = src[e], d = dst[e];
        int pos = atomicAdd(&cursor[d], 1);
        csr_src[pos] = s;
        csr_w[pos] = dinv[s] * dinv[d];
    }
}

// ---------------- weight prep: FRAGMENT-ORDERED layouts ----------------
// Conv B: BF[n16][kq][lane][8], n16=n>>4 (16), kq=k>>5 (8), lane=((k>>3)&3)*16+(n&15), j=k&7.
// A wave's B-fragment load is then 64 consecutive 16-B chunks -> one coalesced 1-KB read.

__global__ void prep_bt_kernel(const float* __restrict__ B, ushort* __restrict__ BF) {
    int n = blockIdx.x, k = threadIdx.x;
    ushort v = f2bf_rne(B[k * 256 + n]);
    int lane = ((k >> 3) & 3) * 16 + (n & 15);
    int idx = ((n >> 4) * 4096) + ((k >> 5) * 512) + lane * 8 + (k & 7);
    BF[idx] = v;
}

// Gate B: rows 0..255 <- gWw, 256..511 <- gUw; hi(trunc)/lo(RNE residual) split;
// BhF/BlF[n16][kq][lane][8] with kq=k>>5 (16).
__global__ void prep_gate_bt_kernel(const float* __restrict__ gWw, const float* __restrict__ gUw,
                                    ushort* __restrict__ BhF, ushort* __restrict__ BlF) {
    int n = blockIdx.x, t = threadIdx.x;
#pragma unroll
    for (int p = 0; p < 2; p++) {
        int k = p * 256 + t;
        float v = (p ? gUw : gWw)[t * 256 + n];
        uint u = __float_as_uint(v);
        ushort hi = (ushort)(u >> 16);
        ushort lo = f2bf_rne(v - __uint_as_float(u & 0xFFFF0000u));
        int lane = ((k >> 3) & 3) * 16 + (n & 15);
        int idx = ((n >> 4) * 8192) + ((k >> 5) * 512) + lane * 8 + (k & 7);
        BhF[idx] = hi; BlF[idx] = lo;
    }
}

// ---------------- MFMA GEMM, ZERO-LDS ZERO-BARRIER ----------------
// 64x128 block, 4 waves (2x2), wave tile 32x64, 16x16x32 MFMA.
// A-fragments: per-lane direct global loads (16 rows x 32B chunks, L2-reused across kq).
// B-fragments: coalesced loads from fragment-ordered BF (L2-resident).
// No __syncthreads anywhere -> waves fully independent, loads pipeline across MFMAs.

__global__ __launch_bounds__(256, 4) void gemm_bf16_kernel(
    const float* __restrict__ A, const ushort* __restrict__ BF,  // BF frag-ordered
    ushort* __restrict__ C, int M)
{
    const int tl = threadIdx.x;
    const int lane = tl & 63, wave = tl >> 6;
    const int wm = (wave & 1) * 32, wn = (wave >> 1) * 64;
    const int bm = blockIdx.x * 64, bn = blockIdx.y * 128;
    const int fr = lane & 15, kg = (lane >> 4) * 8;

    const int r0 = bm + wm + fr, r1 = r0 + 16;
    const bool ok0 = r0 < M, ok1 = r1 < M;
    const float* a0 = A + (size_t)r0 * HIDC + kg;
    const float* a1 = A + (size_t)r1 * HIDC + kg;
    const ushort* bp = BF + (size_t)((bn + wn) >> 4) * 4096 + lane * 8;

    f32x4 acc[2][4] = {};

    for (int kq = 0; kq < 8; kq++) {
        float4 z = make_float4(0.f, 0.f, 0.f, 0.f);
        float4 u0 = z, u1 = z, v0 = z, v1 = z;
        if (ok0) { u0 = *(const float4*)(a0 + kq * 32); u1 = *(const float4*)(a0 + kq * 32 + 4); }
        if (ok1) { v0 = *(const float4*)(a1 + kq * 32); v1 = *(const float4*)(a1 + kq * 32 + 4); }
        short8 af0 = pack8_rne(u0, u1);
        short8 af1 = pack8_rne(v0, v1);
        short8 bfv[4];
#pragma unroll
        for (int nt = 0; nt < 4; nt++)
            bfv[nt] = *(const short8*)(bp + ((size_t)nt * 8 + kq) * 512);
#pragma unroll
        for (int nt = 0; nt < 4; nt++) {
            acc[0][nt] = __builtin_amdgcn_mfma_f32_16x16x32_bf16(af0, bfv[nt], acc[0][nt], 0, 0, 0);
            acc[1][nt] = __builtin_amdgcn_mfma_f32_16x16x32_bf16(af1, bfv[nt], acc[1][nt], 0, 0, 0);
        }
    }

    // epilogue: C/D layout col=lane&15, row=(lane>>4)*4+reg  [m89-verified]
    const int row4 = (lane >> 4) * 4, coln = lane & 15;
#pragma unroll
    for (int mt = 0; mt < 2; mt++)
#pragma unroll
        for (int r = 0; r < 4; r++) {
            int m = bm + wm + mt * 16 + row4 + r;
            if (m < M) {
#pragma unroll
                for (int nt = 0; nt < 4; nt++) {
                    int n = bn + wn + nt * 16 + coln;
                    C[(size_t)m * HIDC + n] = f2bf_rne(acc[mt][nt][r]);
                }
            }
        }
}

// A already bf16 variant (conv2)

__global__ __launch_bounds__(256, 4) void gemm_bf16A_kernel(
    const ushort* __restrict__ A, const ushort* __restrict__ BF,
    ushort* __restrict__ C, int M)
{
    const int tl = threadIdx.x;
    const int lane = tl & 63, wave = tl >> 6;
    const int wm = (wave & 1) * 32, wn = (wave >> 1) * 64;
    const int bm = blockIdx.x * 64, bn = blockIdx.y * 128;
    const int fr = lane & 15, kg = (lane >> 4) * 8;

    const int r0 = bm + wm + fr, r1 = r0 + 16;
    const bool ok0 = r0 < M, ok1 = r1 < M;
    const ushort* a0 = A + (size_t)r0 * HIDC + kg;
    const ushort* a1 = A + (size_t)r1 * HIDC + kg;
    const ushort* bp = BF + (size_t)((bn + wn) >> 4) * 4096 + lane * 8;

    f32x4 acc[2][4] = {};

    for (int kq = 0; kq < 8; kq++) {
        short8 af0 = {}, af1 = {};
        if (ok0) af0 = *(const short8*)(a0 + kq * 32);
        if (ok1) af1 = *(const short8*)(a1 + kq * 32);
        short8 bfv[4];
#pragma unroll
        for (int nt = 0; nt < 4; nt++)
            bfv[nt] = *(const short8*)(bp + ((size_t)nt * 8 + kq) * 512);
#pragma unroll
        for (int nt = 0; nt < 4; nt++) {
            acc[0][nt] = __builtin_amdgcn_mfma_f32_16x16x32_bf16(af0, bfv[nt], acc[0][nt], 0, 0, 0);
            acc[1][nt] = __builtin_amdgcn_mfma_f32_16x16x32_bf16(af1, bfv[nt], acc[1][nt], 0, 0, 0);
        }
    }

    const int row4 = (lane >> 4) * 4, coln = lane & 15;
#pragma unroll
    for (int mt = 0; mt < 2; mt++)
#pragma unroll
        for (int r = 0; r < 4; r++) {
            int m = bm + wm + mt * 16 + row4 + r;
            if (m < M) {
#pragma unroll
                for (int nt = 0; nt < 4; nt++) {
                    int n = bn + wn + nt * 16 + coln;
                    C[(size_t)m * HIDC + n] = f2bf_rne(acc[mt][nt][r]);
                }
            }
        }
}

// ---------------- gate GEMM: zero-LDS, in-register hi/lo split, fused sigmoid blend ----------------
// K=512 = concat(ht, prev); 3-term hi/lo product; same MFMA order as before -> bit-identical.

__global__ __launch_bounds__(256, 4) void gate_kernel(
    const float* __restrict__ ht, const float* __restrict__ prev,
    const ushort* __restrict__ BhF, const ushort* __restrict__ BlF,  // frag-ordered [16][16][64][8]
    const float* __restrict__ gWb, const float* __restrict__ gUb,
    float* __restrict__ out, int M)
{
    const int tl = threadIdx.x;
    const int lane = tl & 63, wave = tl >> 6;
    const int wm = (wave & 1) * 32, wn = (wave >> 1) * 64;
    const int bm = blockIdx.x * 64, bn = blockIdx.y * 128;
    const int fr = lane & 15, kg = (lane >> 4) * 8;

    const int r0 = bm + wm + fr, r1 = r0 + 16;
    const bool ok0 = r0 < M, ok1 = r1 < M;
    const size_t ro0 = (size_t)r0 * HIDC + kg;
    const size_t ro1 = (size_t)r1 * HIDC + kg;
    const ushort* bph = BhF + (size_t)((bn + wn) >> 4) * 8192 + lane * 8;
    const ushort* bpl = BlF + (size_t)((bn + wn) >> 4) * 8192 + lane * 8;

    f32x4 acc[2][4] = {};

    for (int kq = 0; kq < 16; kq++) {
        const float* S = (kq < 8) ? ht : prev;
        const int cb = (kq & 7) * 32;
        float4 z = make_float4(0.f, 0.f, 0.f, 0.f);
        float4 u0 = z, u1 = z, v0 = z, v1 = z;
        if (ok0) { u0 = *(const float4*)(S + ro0 + cb); u1 = *(const float4*)(S + ro0 + cb + 4); }
        if (ok1) { v0 = *(const float4*)(S + ro1 + cb); v1 = *(const float4*)(S + ro1 + cb + 4); }
        short8 ah0, al0, ah1, al1;
        split8(u0, u1, ah0, al0);
        split8(v0, v1, ah1, al1);
        short8 bfh[4], bfl[4];
#pragma unroll
        for (int nt = 0; nt < 4; nt++) {
            size_t off = ((size_t)nt * 16 + kq) * 512;
            bfh[nt] = *(const short8*)(bph + off);
            bfl[nt] = *(const short8*)(bpl + off);
        }
#pragma unroll
        for (int nt = 0; nt < 4; nt++) {
            acc[0][nt] = __builtin_amdgcn_mfma_f32_16x16x32_bf16(ah0, bfh[nt], acc[0][nt], 0, 0, 0);
            acc[0][nt] = __builtin_amdgcn_mfma_f32_16x16x32_bf16(ah0, bfl[nt], acc[0][nt], 0, 0, 0);
            acc[0][nt] = __builtin_amdgcn_mfma_f32_16x16x32_bf16(al0, bfh[nt], acc[0][nt], 0, 0, 0);
            acc[1][nt] = __builtin_amdgcn_mfma_f32_16x16x32_bf16(ah1, bfh[nt], acc[1][nt], 0, 0, 0);
            acc[1][nt] = __builtin_amdgcn_mfma_f32_16x16x32_bf16(ah1, bfl[nt], acc[1][nt], 0, 0, 0);
            acc[1][nt] = __builtin_amdgcn_mfma_f32_16x16x32_bf16(al1, bfh[nt], acc[1][nt], 0, 0, 0);
        }
    }

    const int row4 = (lane >> 4) * 4, coln = lane & 15;
#pragma unroll
    for (int mt = 0; mt < 2; mt++)
#pragma unroll
        for (int r = 0; r < 4; r++) {
            int m = bm + wm + mt * 16 + row4 + r;
            if (m < M) {
#pragma unroll
                for (int nt = 0; nt < 4; nt++) {
                    int n = bn + wn + nt * 16 + coln;
                    size_t idx = (size_t)m * HIDC + n;
                    float g = acc[mt][nt][r] + gWb[n] + gUb[n];
                    float alpha = 1.f / (1.f + expf(-g));
                    out[idx] = alpha * ht[idx] + (1.f - alpha) * prev[idx];
                }
            }
        }
}

// ---------------- CSR aggregation: one WAVE per row, ushort4 gathers, 4-deep unroll ----------------

__global__ __launch_bounds__(256) void csr_agg_kernel(
    const ushort* __restrict__ hm, const int* __restrict__ row_start,
    const int* __restrict__ csr_src, const float* __restrict__ csr_w,
    const float* __restrict__ dinv, const float* __restrict__ bias,
    float* __restrict__ outf, ushort* __restrict__ outb, int do_relu, int N)
{
    const int wave = threadIdx.x >> 6, lane = threadIdx.x & 63;
    const int i = blockIdx.x * 4 + wave;
    if (i >= N) return;
    const int c = lane * 4;

    const float di = dinv[i];
    const float s2 = di * di;
    ushort4 sv = *(const ushort4*)(hm + (size_t)i * HIDC + c);
    float a0 = s2 * bf2f(sv.x), a1 = s2 * bf2f(sv.y);
    float a2 = s2 * bf2f(sv.z), a3 = s2 * bf2f(sv.w);

    const int b0 = row_start[i], b1 = row_start[i + 1];
    int t = b0;
    for (; t + 4 <= b1; t += 4) {
        int   i0 = csr_src[t],     i1 = csr_src[t + 1];
        int   i2 = csr_src[t + 2], i3 = csr_src[t + 3];
        float w0 = csr_w[t],       w1 = csr_w[t + 1];
        float w2 = csr_w[t + 2],   w3 = csr_w[t + 3];
        ushort4 v0 = *(const ushort4*)(hm + (size_t)i0 * HIDC + c);
        ushort4 v1 = *(const ushort4*)(hm + (size_t)i1 * HIDC + c);
        ushort4 v2 = *(const ushort4*)(hm + (size_t)i2 * HIDC + c);
        ushort4 v3 = *(const ushort4*)(hm + (size_t)i3 * HIDC + c);
        a0 += w0 * bf2f(v0.x); a1 += w0 * bf2f(v0.y); a2 += w0 * bf2f(v0.z); a3 += w0 * bf2f(v0.w);
        a0 += w1 * bf2f(v1.x); a1 += w1 * bf2f(v1.y); a2 += w1 * bf2f(v1.z); a3 += w1 * bf2f(v1.w);
        a0 += w2 * bf2f(v2.x); a1 += w2 * bf2f(v2.y); a2 += w2 * bf2f(v2.z); a3 += w2 * bf2f(v2.w);
        a0 += w3 * bf2f(v3.x); a1 += w3 * bf2f(v3.y); a2 += w3 * bf2f(v3.z); a3 += w3 * bf2f(v3.w);
    }
    for (; t < b1; ++t) {
        int s_ = csr_src[t];
        float w = csr_w[t];
        ushort4 v = *(const ushort4*)(hm + (size_t)s_ * HIDC + c);
        a0 += w * bf2f(v.x); a1 += w * bf2f(v.y); a2 += w * bf2f(v.z); a3 += w * bf2f(v.w);
    }

    float4 bb = *(const float4*)(bias + c);
    a0 += bb.x; a1 += bb.y; a2 += bb.z; a3 += bb.w;
    if (do_relu) {
        a0 = fmaxf(a0, 0.f); a1 = fmaxf(a1, 0.f);
        a2 = fmaxf(a2, 0.f); a3 = fmaxf(a3, 0.f);
    }
    if (outb) {
        ushort4 o;
        o.x = f2bf_rne(a0); o.y = f2bf_rne(a1);
        o.z = f2bf_rne(a2); o.w = f2bf_rne(a3);
        *(ushort4*)(outb + (size_t)i * HIDC + c) = o;
    } else {
        *(float4*)(outf + (size_t)i * HIDC + c) = make_float4(a0, a1, a2, a3);
    }
}

// ---------------- launch ----------------

extern "C" void kernel_launch(void* const* d_in, const int* in_sizes, int n_in,
                              void* d_out, int out_size, void* d_ws, size_t ws_size,
                              hipStream_t stream) {
    const float* x    = (const float*)d_in[0];
    const int*   ei   = (const int*)d_in[1];
    const float* prev = (const float*)d_in[2];
    const float* W1   = (const float*)d_in[3];
    const float* b1   = (const float*)d_in[4];
    const float* W2   = (const float*)d_in[5];
    const float* b2   = (const float*)d_in[6];
    const float* gWw  = (const float*)d_in[7];
    const float* gWb  = (const float*)d_in[8];
    const float* gUw  = (const float*)d_in[9];
    const float* gUb  = (const float*)d_in[10];

    const int N = in_sizes[0] / HIDC;
    const int E = in_sizes[1] / 2;
    const int* src = ei;
    const int* dst = ei + E;

    float* out  = (float*)d_out;
    float* out1 = out;                       // h_tilde region (scratch first: h bf16)
    float* ht   = out + (size_t)N * HIDC;    // h_t region (f32)
    ushort* hbf = (ushort*)out1;             // bf16 h lives in out1 region until gate overwrites it

    // workspace layout (float units, 64-aligned chunks)
    float* ws = (float*)d_ws;
    size_t o = 0;
    auto take = [&](size_t n) { size_t r = o; o += (n + 63) & ~(size_t)63; return r; };
    float*  dinv    = ws + take(N);
    int*    degi    = (int*)(ws + take(N));
    int*    row_st  = (int*)(ws + take(N + 1));
    int*    cursor  = (int*)(ws + take(N + 1));
    int*    csr_src = (int*)(ws + take(E));
    float*  csr_w   = ws + take(E);
    ushort* Bt1F    = (ushort*)(ws + take(256 * 256 / 2));
    ushort* Bt2F    = (ushort*)(ws + take(256 * 256 / 2));
    ushort* BthF    = (ushort*)(ws + take(256 * 512 / 2));
    ushort* BtlF    = (ushort*)(ws + take(256 * 512 / 2));
    ushort* hm      = (ushort*)(ws + take((size_t)N * HIDC / 2));

    const int nbN = (N + 255) / 256;
    const int nbE = (E + 255) / 256;
    dim3 ggrid((N + 63) / 64, 2);
    const int nbAgg = (N + 3) / 4;

    // ---- CSR build ----
    int* blocksum = (int*)csr_w;  // free until scatter_kernel
    fill_i_kernel<<<nbN, 256, 0, stream>>>(degi, 0, N);
    deg_kernel<<<nbE, 256, 0, stream>>>(dst, degi, E);
    scan_a_kernel<<<nbN, 256, 0, stream>>>(degi, row_st, blocksum, N);
    scan_b_kernel<<<1, 256, 0, stream>>>(blocksum, nbN);
    scan_c_kernel<<<nbN, 256, 0, stream>>>(row_st, cursor, blocksum, N);
    rsqrt_kernel<<<nbN, 256, 0, stream>>>(degi, dinv, N);
    scatter_kernel<<<nbE, 256, 0, stream>>>(src, dst, dinv, cursor, csr_src, csr_w, E);

    // ---- weight prep (fragment-ordered) ----
    prep_bt_kernel<<<256, 256, 0, stream>>>(W1, Bt1F);
    prep_bt_kernel<<<256, 256, 0, stream>>>(W2, Bt2F);
    prep_gate_bt_kernel<<<256, 256, 0, stream>>>(gWw, gUw, BthF, BtlF);

    // ---- conv1 ----
    gemm_bf16_kernel<<<ggrid, 256, 0, stream>>>(x, Bt1F, hm, N);
    csr_agg_kernel<<<nbAgg, 256, 0, stream>>>(hm, row_st, csr_src, csr_w, dinv, b1,
                                              nullptr, hbf, 1, N);

    // ---- conv2 (A already bf16) ----
    gemm_bf16A_kernel<<<ggrid, 256, 0, stream>>>(hbf, Bt2F, hm, N);
    csr_agg_kernel<<<nbAgg, 256, 0, stream>>>(hm, row_st, csr_src, csr_w, dinv, b2,
                                              ht, nullptr, 0, N);

    // ---- gate (fused final; overwrites hbf region, which is fully consumed) ----
    gate_kernel<<<ggrid, 256, 0, stream>>>(ht, prev, BthF, BtlF, gWb, gUb, out1, N);

    (void)n_in; (void)out_size; (void)ws_size;
}

// Round 6
// 549.030 us; speedup vs baseline: 1.0333x; 1.0333x over previous
//
#include <hip/hip_runtime.h>
#include <hip/hip_bf16.h>
#include <math.h>

#define HIDC 256

typedef short short8 __attribute__((ext_vector_type(8)));
typedef float f32x4 __attribute__((ext_vector_type(4)));

__device__ __forceinline__ ushort f2bf_rne(float f) {
    uint u = __float_as_uint(f);
    u += 0x7FFF + ((u >> 16) & 1);
    return (ushort)(u >> 16);
}
__device__ __forceinline__ float bf2f(ushort h) {
    return __uint_as_float(((uint)h) << 16);
}
__device__ __forceinline__ f32x4 MF(short8 a, short8 b, f32x4 c) {
    return __builtin_amdgcn_mfma_f32_16x16x32_bf16(a, b, c, 0, 0, 0);
}

// pack 8 f32 -> short8 bf16 RNE (all const-indexed -> stays in registers)
__device__ __forceinline__ short8 pack8_rne(float4 a, float4 b) {
    ushort h[8];
    h[0] = f2bf_rne(a.x); h[1] = f2bf_rne(a.y); h[2] = f2bf_rne(a.z); h[3] = f2bf_rne(a.w);
    h[4] = f2bf_rne(b.x); h[5] = f2bf_rne(b.y); h[6] = f2bf_rne(b.z); h[7] = f2bf_rne(b.w);
    return *(short8*)h;
}
// split 8 f32 into hi (truncated bf16) + lo (RNE of residual) -- identical to staged split
__device__ __forceinline__ void split8(float4 a, float4 b, short8& hi, short8& lo) {
    float v[8] = {a.x, a.y, a.z, a.w, b.x, b.y, b.z, b.w};
    ushort hh[8], ll[8];
#pragma unroll
    for (int q = 0; q < 8; q++) {
        uint u = __float_as_uint(v[q]);
        hh[q] = (ushort)(u >> 16);
        ll[q] = f2bf_rne(v[q] - __uint_as_float(u & 0xFFFF0000u));
    }
    hi = *(short8*)hh; lo = *(short8*)ll;
}

// ---------------- small utility kernels ----------------

__global__ void fill_i_kernel(int* __restrict__ p, int v, int n) {
    int i = blockIdx.x * 256 + threadIdx.x;
    if (i < n) p[i] = v;
}

__global__ void deg_kernel(const int* __restrict__ dst, int* __restrict__ deg, int E) {
    int e = blockIdx.x * 256 + threadIdx.x;
    if (e < E) atomicAdd(&deg[dst[e]], 1);
}

__global__ void rsqrt_kernel(const int* __restrict__ deg, float* __restrict__ dinv, int n) {
    int i = blockIdx.x * 256 + threadIdx.x;
    if (i < n) dinv[i] = rsqrtf((float)(deg[i] + 1));   // +1 = self-loop
}

// ---------------- 3-kernel exclusive scan ----------------

__device__ __forceinline__ int block_incl_scan(int v, int tid) {
#pragma unroll
    for (int off = 1; off < 64; off <<= 1) {
        int t = __shfl_up(v, off);
        if ((tid & 63) >= off) v += t;
    }
    __shared__ int wt[4];
    if ((tid & 63) == 63) wt[tid >> 6] = v;
    __syncthreads();
    int wid = tid >> 6;
    for (int w = 0; w < wid; w++) v += wt[w];
    __syncthreads();
    return v;
}

__global__ void scan_a_kernel(const int* __restrict__ deg, int* __restrict__ row_start,
                              int* __restrict__ blocksum, int N) {
    int tid = threadIdx.x;
    int i = blockIdx.x * 256 + tid;
    int v = (i < N) ? deg[i] : 0;
    int incl = block_incl_scan(v, tid);
    if (i < N) row_start[i + 1] = incl;
    if (tid == 255) blocksum[blockIdx.x] = incl;
}

__global__ void scan_b_kernel(int* __restrict__ blocksum, int nb) {
    int tid = threadIdx.x;
    int v = (tid < nb) ? blocksum[tid] : 0;
    int incl = block_incl_scan(v, tid);
    if (tid < nb) blocksum[tid] = incl;
}

__global__ void scan_c_kernel(int* __restrict__ row_start, int* __restrict__ cursor,
                              const int* __restrict__ blocksum, int N) {
    int b = blockIdx.x;
    int i = b * 256 + threadIdx.x;
    int add = (b > 0) ? blocksum[b - 1] : 0;
    if (i < N) {
        int v = row_start[i + 1] + add;
        row_start[i + 1] = v;
        cursor[i + 1] = v;
    }
    if (b == 0 && threadIdx.x == 0) { row_start[0] = 0; cursor[0] = 0; }
}

__global__ void scatter_kernel(const int* __restrict__ src, const int* __restrict__ dst,
                               const float* __restrict__ dinv, int* __restrict__ cursor,
                               int* __restrict__ csr_src, float* __restrict__ csr_w, int E) {
    int e = blockIdx.x * 256 + threadIdx.x;
    if (e < E) {
        int s = src[e], d = dst[e];
        int pos = atomicAdd(&cursor[d], 1);
        csr_src[pos] = s;
        csr_w[pos] = dinv[s] * dinv[d];
    }
}

// ---------------- weight prep: FRAGMENT-ORDERED layouts ----------------
// Conv B: BF[n16][kq][lane][8], n16=n>>4 (16), kq=k>>5 (8), lane=((k>>3)&3)*16+(n&15), j=k&7.

__global__ void prep_bt_kernel(const float* __restrict__ B, ushort* __restrict__ BF) {
    int n = blockIdx.x, k = threadIdx.x;
    ushort v = f2bf_rne(B[k * 256 + n]);
    int lane = ((k >> 3) & 3) * 16 + (n & 15);
    int idx = ((n >> 4) * 4096) + ((k >> 5) * 512) + lane * 8 + (k & 7);
    BF[idx] = v;
}

// Gate B: rows 0..255 <- gWw, 256..511 <- gUw; hi(trunc)/lo(RNE residual) split.
__global__ void prep_gate_bt_kernel(const float* __restrict__ gWw, const float* __restrict__ gUw,
                                    ushort* __restrict__ BhF, ushort* __restrict__ BlF) {
    int n = blockIdx.x, t = threadIdx.x;
#pragma unroll
    for (int p = 0; p < 2; p++) {
        int k = p * 256 + t;
        float v = (p ? gUw : gWw)[t * 256 + n];
        uint u = __float_as_uint(v);
        ushort hi = (ushort)(u >> 16);
        ushort lo = f2bf_rne(v - __uint_as_float(u & 0xFFFF0000u));
        int lane = ((k >> 3) & 3) * 16 + (n & 7) + ((k >> 3) & 0) ; // placeholder, fixed below
        lane = ((k >> 3) & 3) * 16 + (n & 15);
        int idx = ((n >> 4) * 8192) + ((k >> 5) * 512) + lane * 8 + (k & 7);
        BhF[idx] = hi; BlF[idx] = lo;
    }
}

// ---------------- MFMA GEMM, zero-LDS + explicit 2-deep register double-buffer ----------------
// 64x128 block, 4 waves (2x2), wave tile 32x64. Fully unrolled kq loop; loads for set k+1
// issue BEFORE MFMAs of set k -> waitcnt lands after the MFMA burst (deterministic pipelining).

__global__ __launch_bounds__(256, 3) void gemm_bf16_kernel(
    const float* __restrict__ A, const ushort* __restrict__ BF,
    ushort* __restrict__ C, int M)
{
    const int tl = threadIdx.x;
    const int lane = tl & 63, wave = tl >> 6;
    const int wm = (wave & 1) * 32, wn = (wave >> 1) * 64;
    const int bm = blockIdx.x * 64, bn = blockIdx.y * 128;
    const int fr = lane & 15, kg = (lane >> 4) * 8;

    const int r0 = bm + wm + fr, r1 = r0 + 16;
    const bool ok0 = r0 < M, ok1 = r1 < M;
    const float* a0 = A + (size_t)r0 * HIDC + kg;
    const float* a1 = A + (size_t)r1 * HIDC + kg;
    const ushort* bp = BF + (size_t)((bn + wn) >> 4) * 4096 + lane * 8;

    f32x4 acc[2][4] = {};
    float4 uA0, uA1, vA0, vA1, uB0, uB1, vB0, vB1;
    short8 bA[4], bB[4];

#define C_LOADA(kq, U0, U1, V0, V1) { \
    float4 z = make_float4(0.f, 0.f, 0.f, 0.f); \
    U0 = z; U1 = z; V0 = z; V1 = z; \
    if (ok0) { U0 = *(const float4*)(a0 + (kq) * 32); U1 = *(const float4*)(a0 + (kq) * 32 + 4); } \
    if (ok1) { V0 = *(const float4*)(a1 + (kq) * 32); V1 = *(const float4*)(a1 + (kq) * 32 + 4); } }

#define C_LOADB(kq, B_) { \
    _Pragma("unroll") \
    for (int nt = 0; nt < 4; nt++) \
        B_[nt] = *(const short8*)(bp + ((size_t)nt * 8 + (kq)) * 512); }

#define C_MFMA(U0, U1, V0, V1, B_) { \
    short8 af0 = pack8_rne(U0, U1); \
    short8 af1 = pack8_rne(V0, V1); \
    _Pragma("unroll") \
    for (int nt = 0; nt < 4; nt++) { \
        acc[0][nt] = MF(af0, B_[nt], acc[0][nt]); \
        acc[1][nt] = MF(af1, B_[nt], acc[1][nt]); } }

    C_LOADA(0, uA0, uA1, vA0, vA1); C_LOADB(0, bA);
#pragma unroll
    for (int kq = 0; kq < 8; kq += 2) {
        C_LOADA(kq + 1, uB0, uB1, vB0, vB1); C_LOADB(kq + 1, bB);
        C_MFMA(uA0, uA1, vA0, vA1, bA);
        if (kq + 2 < 8) { C_LOADA(kq + 2, uA0, uA1, vA0, vA1); C_LOADB(kq + 2, bA); }
        C_MFMA(uB0, uB1, vB0, vB1, bB);
    }

    // epilogue: C/D layout col=lane&15, row=(lane>>4)*4+reg  [m89-verified]
    const int row4 = (lane >> 4) * 4, coln = lane & 15;
#pragma unroll
    for (int mt = 0; mt < 2; mt++)
#pragma unroll
        for (int r = 0; r < 4; r++) {
            int m = bm + wm + mt * 16 + row4 + r;
            if (m < M) {
#pragma unroll
                for (int nt = 0; nt < 4; nt++) {
                    int n = bn + wn + nt * 16 + coln;
                    C[(size_t)m * HIDC + n] = f2bf_rne(acc[mt][nt][r]);
                }
            }
        }
}

// A already bf16 variant (conv2)

__global__ __launch_bounds__(256, 3) void gemm_bf16A_kernel(
    const ushort* __restrict__ A, const ushort* __restrict__ BF,
    ushort* __restrict__ C, int M)
{
    const int tl = threadIdx.x;
    const int lane = tl & 63, wave = tl >> 6;
    const int wm = (wave & 1) * 32, wn = (wave >> 1) * 64;
    const int bm = blockIdx.x * 64, bn = blockIdx.y * 128;
    const int fr = lane & 15, kg = (lane >> 4) * 8;

    const int r0 = bm + wm + fr, r1 = r0 + 16;
    const bool ok0 = r0 < M, ok1 = r1 < M;
    const ushort* a0 = A + (size_t)r0 * HIDC + kg;
    const ushort* a1 = A + (size_t)r1 * HIDC + kg;
    const ushort* bp = BF + (size_t)((bn + wn) >> 4) * 4096 + lane * 8;

    f32x4 acc[2][4] = {};
    short8 fA0, fA1, fB0, fB1;
    short8 bA[4], bB[4];

#define H_LOADA(kq, F0, F1) { \
    short8 z = {}; F0 = z; F1 = z; \
    if (ok0) F0 = *(const short8*)(a0 + (kq) * 32); \
    if (ok1) F1 = *(const short8*)(a1 + (kq) * 32); }

#define H_MFMA(F0, F1, B_) { \
    _Pragma("unroll") \
    for (int nt = 0; nt < 4; nt++) { \
        acc[0][nt] = MF(F0, B_[nt], acc[0][nt]); \
        acc[1][nt] = MF(F1, B_[nt], acc[1][nt]); } }

    H_LOADA(0, fA0, fA1); C_LOADB(0, bA);
#pragma unroll
    for (int kq = 0; kq < 8; kq += 2) {
        H_LOADA(kq + 1, fB0, fB1); C_LOADB(kq + 1, bB);
        H_MFMA(fA0, fA1, bA);
        if (kq + 2 < 8) { H_LOADA(kq + 2, fA0, fA1); C_LOADB(kq + 2, bA); }
        H_MFMA(fB0, fB1, bB);
    }

    const int row4 = (lane >> 4) * 4, coln = lane & 15;
#pragma unroll
    for (int mt = 0; mt < 2; mt++)
#pragma unroll
        for (int r = 0; r < 4; r++) {
            int m = bm + wm + mt * 16 + row4 + r;
            if (m < M) {
#pragma unroll
                for (int nt = 0; nt < 4; nt++) {
                    int n = bn + wn + nt * 16 + coln;
                    C[(size_t)m * HIDC + n] = f2bf_rne(acc[mt][nt][r]);
                }
            }
        }
}

// ---------------- gate GEMM: zero-LDS, in-register hi/lo split, double-buffered ----------------
// K=512 = concat(ht, prev); MFMA order identical to previous rounds -> bit-identical output.

__global__ __launch_bounds__(256, 2) void gate_kernel(
    const float* __restrict__ ht, const float* __restrict__ prev,
    const ushort* __restrict__ BhF, const ushort* __restrict__ BlF,
    const float* __restrict__ gWb, const float* __restrict__ gUb,
    float* __restrict__ out, int M)
{
    const int tl = threadIdx.x;
    const int lane = tl & 63, wave = tl >> 6;
    const int wm = (wave & 1) * 32, wn = (wave >> 1) * 64;
    const int bm = blockIdx.x * 64, bn = blockIdx.y * 128;
    const int fr = lane & 15, kg = (lane >> 4) * 8;

    const int r0 = bm + wm + fr, r1 = r0 + 16;
    const bool ok0 = r0 < M, ok1 = r1 < M;
    const size_t ro0 = (size_t)r0 * HIDC + kg;
    const size_t ro1 = (size_t)r1 * HIDC + kg;
    const ushort* bph = BhF + (size_t)((bn + wn) >> 4) * 8192 + lane * 8;
    const ushort* bpl = BlF + (size_t)((bn + wn) >> 4) * 8192 + lane * 8;

    f32x4 acc[2][4] = {};
    float4 uA0, uA1, vA0, vA1, uB0, uB1, vB0, vB1;
    short8 bhA[4], blA[4], bhB[4], blB[4];

#define G_LOADA(kq, U0, U1, V0, V1) { \
    const float* S = ((kq) < 8) ? ht : prev; \
    const int cb = ((kq) & 7) * 32; \
    float4 z = make_float4(0.f, 0.f, 0.f, 0.f); \
    U0 = z; U1 = z; V0 = z; V1 = z; \
    if (ok0) { U0 = *(const float4*)(S + ro0 + cb); U1 = *(const float4*)(S + ro0 + cb + 4); } \
    if (ok1) { V0 = *(const float4*)(S + ro1 + cb); V1 = *(const float4*)(S + ro1 + cb + 4); } }

#define G_LOADB(kq, BH, BL) { \
    _Pragma("unroll") \
    for (int nt = 0; nt < 4; nt++) { \
        size_t off = ((size_t)nt * 16 + (kq)) * 512; \
        BH[nt] = *(const short8*)(bph + off); \
        BL[nt] = *(const short8*)(bpl + off); } }

#define G_MFMA(U0, U1, V0, V1, BH, BL) { \
    short8 ah0, al0, ah1, al1; \
    split8(U0, U1, ah0, al0); \
    split8(V0, V1, ah1, al1); \
    _Pragma("unroll") \
    for (int nt = 0; nt < 4; nt++) { \
        acc[0][nt] = MF(ah0, BH[nt], acc[0][nt]); \
        acc[0][nt] = MF(ah0, BL[nt], acc[0][nt]); \
        acc[0][nt] = MF(al0, BH[nt], acc[0][nt]); \
        acc[1][nt] = MF(ah1, BH[nt], acc[1][nt]); \
        acc[1][nt] = MF(ah1, BL[nt], acc[1][nt]); \
        acc[1][nt] = MF(al1, BH[nt], acc[1][nt]); } }

    G_LOADA(0, uA0, uA1, vA0, vA1); G_LOADB(0, bhA, blA);
#pragma unroll
    for (int kq = 0; kq < 16; kq += 2) {
        G_LOADA(kq + 1, uB0, uB1, vB0, vB1); G_LOADB(kq + 1, bhB, blB);
        G_MFMA(uA0, uA1, vA0, vA1, bhA, blA);
        if (kq + 2 < 16) { G_LOADA(kq + 2, uA0, uA1, vA0, vA1); G_LOADB(kq + 2, bhA, blA); }
        G_MFMA(uB0, uB1, vB0, vB1, bhB, blB);
    }

    const int row4 = (lane >> 4) * 4, coln = lane & 15;
#pragma unroll
    for (int mt = 0; mt < 2; mt++)
#pragma unroll
        for (int r = 0; r < 4; r++) {
            int m = bm + wm + mt * 16 + row4 + r;
            if (m < M) {
#pragma unroll
                for (int nt = 0; nt < 4; nt++) {
                    int n = bn + wn + nt * 16 + coln;
                    size_t idx = (size_t)m * HIDC + n;
                    float g = acc[mt][nt][r] + gWb[n] + gUb[n];
                    float alpha = 1.f / (1.f + expf(-g));
                    out[idx] = alpha * ht[idx] + (1.f - alpha) * prev[idx];
                }
            }
        }
}

// ---------------- CSR aggregation: one WAVE per row, ushort4 gathers, 4-deep unroll ----------------

__global__ __launch_bounds__(256) void csr_agg_kernel(
    const ushort* __restrict__ hm, const int* __restrict__ row_start,
    const int* __restrict__ csr_src, const float* __restrict__ csr_w,
    const float* __restrict__ dinv, const float* __restrict__ bias,
    float* __restrict__ outf, ushort* __restrict__ outb, int do_relu, int N)
{
    const int wave = threadIdx.x >> 6, lane = threadIdx.x & 63;
    const int i = blockIdx.x * 4 + wave;
    if (i >= N) return;
    const int c = lane * 4;

    const float di = dinv[i];
    const float s2 = di * di;
    ushort4 sv = *(const ushort4*)(hm + (size_t)i * HIDC + c);
    float a0 = s2 * bf2f(sv.x), a1 = s2 * bf2f(sv.y);
    float a2 = s2 * bf2f(sv.z), a3 = s2 * bf2f(sv.w);

    const int b0 = row_start[i], b1 = row_start[i + 1];
    int t = b0;
    for (; t + 4 <= b1; t += 4) {
        int   i0 = csr_src[t],     i1 = csr_src[t + 1];
        int   i2 = csr_src[t + 2], i3 = csr_src[t + 3];
        float w0 = csr_w[t],       w1 = csr_w[t + 1];
        float w2 = csr_w[t + 2],   w3 = csr_w[t + 3];
        ushort4 v0 = *(const ushort4*)(hm + (size_t)i0 * HIDC + c);
        ushort4 v1 = *(const ushort4*)(hm + (size_t)i1 * HIDC + c);
        ushort4 v2 = *(const ushort4*)(hm + (size_t)i2 * HIDC + c);
        ushort4 v3 = *(const ushort4*)(hm + (size_t)i3 * HIDC + c);
        a0 += w0 * bf2f(v0.x); a1 += w0 * bf2f(v0.y); a2 += w0 * bf2f(v0.z); a3 += w0 * bf2f(v0.w);
        a0 += w1 * bf2f(v1.x); a1 += w1 * bf2f(v1.y); a2 += w1 * bf2f(v1.z); a3 += w1 * bf2f(v1.w);
        a0 += w2 * bf2f(v2.x); a1 += w2 * bf2f(v2.y); a2 += w2 * bf2f(v2.z); a3 += w2 * bf2f(v2.w);
        a0 += w3 * bf2f(v3.x); a1 += w3 * bf2f(v3.y); a2 += w3 * bf2f(v3.z); a3 += w3 * bf2f(v3.w);
    }
    for (; t < b1; ++t) {
        int s_ = csr_src[t];
        float w = csr_w[t];
        ushort4 v = *(const ushort4*)(hm + (size_t)s_ * HIDC + c);
        a0 += w * bf2f(v.x); a1 += w * bf2f(v.y); a2 += w * bf2f(v.z); a3 += w * bf2f(v.w);
    }

    float4 bb = *(const float4*)(bias + c);
    a0 += bb.x; a1 += bb.y; a2 += bb.z; a3 += bb.w;
    if (do_relu) {
        a0 = fmaxf(a0, 0.f); a1 = fmaxf(a1, 0.f);
        a2 = fmaxf(a2, 0.f); a3 = fmaxf(a3, 0.f);
    }
    if (outb) {
        ushort4 o;
        o.x = f2bf_rne(a0); o.y = f2bf_rne(a1);
        o.z = f2bf_rne(a2); o.w = f2bf_rne(a3);
        *(ushort4*)(outb + (size_t)i * HIDC + c) = o;
    } else {
        *(float4*)(outf + (size_t)i * HIDC + c) = make_float4(a0, a1, a2, a3);
    }
}

// ---------------- launch ----------------

extern "C" void kernel_launch(void* const* d_in, const int* in_sizes, int n_in,
                              void* d_out, int out_size, void* d_ws, size_t ws_size,
                              hipStream_t stream) {
    const float* x    = (const float*)d_in[0];
    const int*   ei   = (const int*)d_in[1];
    const float* prev = (const float*)d_in[2];
    const float* W1   = (const float*)d_in[3];
    const float* b1   = (const float*)d_in[4];
    const float* W2   = (const float*)d_in[5];
    const float* b2   = (const float*)d_in[6];
    const float* gWw  = (const float*)d_in[7];
    const float* gWb  = (const float*)d_in[8];
    const float* gUw  = (const float*)d_in[9];
    const float* gUb  = (const float*)d_in[10];

    const int N = in_sizes[0] / HIDC;
    const int E = in_sizes[1] / 2;
    const int* src = ei;
    const int* dst = ei + E;

    float* out  = (float*)d_out;
    float* out1 = out;                       // h_tilde region (scratch first: h bf16)
    float* ht   = out + (size_t)N * HIDC;    // h_t region (f32)
    ushort* hbf = (ushort*)out1;             // bf16 h lives in out1 region until gate overwrites it

    // workspace layout (float units, 64-aligned chunks)
    float* ws = (float*)d_ws;
    size_t o = 0;
    auto take = [&](size_t n) { size_t r = o; o += (n + 63) & ~(size_t)63; return r; };
    float*  dinv    = ws + take(N);
    int*    degi    = (int*)(ws + take(N));
    int*    row_st  = (int*)(ws + take(N + 1));
    int*    cursor  = (int*)(ws + take(N + 1));
    int*    csr_src = (int*)(ws + take(E));
    float*  csr_w   = ws + take(E);
    ushort* Bt1F    = (ushort*)(ws + take(256 * 256 / 2));
    ushort* Bt2F    = (ushort*)(ws + take(256 * 256 / 2));
    ushort* BthF    = (ushort*)(ws + take(256 * 512 / 2));
    ushort* BtlF    = (ushort*)(ws + take(256 * 512 / 2));
    ushort* hm      = (ushort*)(ws + take((size_t)N * HIDC / 2));

    const int nbN = (N + 255) / 256;
    const int nbE = (E + 255) / 256;
    dim3 ggrid((N + 63) / 64, 2);
    const int nbAgg = (N + 3) / 4;

    // ---- CSR build ----
    int* blocksum = (int*)csr_w;  // free until scatter_kernel
    fill_i_kernel<<<nbN, 256, 0, stream>>>(degi, 0, N);
    deg_kernel<<<nbE, 256, 0, stream>>>(dst, degi, E);
    scan_a_kernel<<<nbN, 256, 0, stream>>>(degi, row_st, blocksum, N);
    scan_b_kernel<<<1, 256, 0, stream>>>(blocksum, nbN);
    scan_c_kernel<<<nbN, 256, 0, stream>>>(row_st, cursor, blocksum, N);
    rsqrt_kernel<<<nbN, 256, 0, stream>>>(degi, dinv, N);
    scatter_kernel<<<nbE, 256, 0, stream>>>(src, dst, dinv, cursor, csr_src, csr_w, E);

    // ---- weight prep (fragment-ordered) ----
    prep_bt_kernel<<<256, 256, 0, stream>>>(W1, Bt1F);
    prep_bt_kernel<<<256, 256, 0, stream>>>(W2, Bt2F);
    prep_gate_bt_kernel<<<256, 256, 0, stream>>>(gWw, gUw, BthF, BtlF);

    // ---- conv1 ----
    gemm_bf16_kernel<<<ggrid, 256, 0, stream>>>(x, Bt1F, hm, N);
    csr_agg_kernel<<<nbAgg, 256, 0, stream>>>(hm, row_st, csr_src, csr_w, dinv, b1,
                                              nullptr, hbf, 1, N);

    // ---- conv2 (A already bf16) ----
    gemm_bf16A_kernel<<<ggrid, 256, 0, stream>>>(hbf, Bt2F, hm, N);
    csr_agg_kernel<<<nbAgg, 256, 0, stream>>>(hm, row_st, csr_src, csr_w, dinv, b2,
                                              ht, nullptr, 0, N);

    // ---- gate (fused final; overwrites hbf region, which is fully consumed) ----
    gate_kernel<<<ggrid, 256, 0, stream>>>(ht, prev, BthF, BtlF, gWb, gUb, out1, N);

    (void)n_in; (void)out_size; (void)ws_size;
}

// Round 9
// 523.365 us; speedup vs baseline: 1.0840x; 1.0490x over previous
//
#include <hip/hip_runtime.h>
#include <hip/hip_bf16.h>
#include <math.h>

#define HIDC 256
#define ALD 40   // A-tile LDS row stride in ushorts (80 B, 16B-aligned, <=2-way bank alias = free)

typedef short short8 __attribute__((ext_vector_type(8)));
typedef float f32x4 __attribute__((ext_vector_type(4)));

__device__ __forceinline__ ushort f2bf_rne(float f) {
    uint u = __float_as_uint(f);
    u += 0x7FFF + ((u >> 16) & 1);
    return (ushort)(u >> 16);
}
__device__ __forceinline__ float bf2f(ushort h) {
    return __uint_as_float(((uint)h) << 16);
}
__device__ __forceinline__ f32x4 MF(short8 a, short8 b, f32x4 c) {
    return __builtin_amdgcn_mfma_f32_16x16x32_bf16(a, b, c, 0, 0, 0);
}

// pack 8 f32 -> short8 bf16 RNE (const-indexed -> registers)
__device__ __forceinline__ short8 pack8_rne(float4 a, float4 b) {
    ushort h[8];
    h[0] = f2bf_rne(a.x); h[1] = f2bf_rne(a.y); h[2] = f2bf_rne(a.z); h[3] = f2bf_rne(a.w);
    h[4] = f2bf_rne(b.x); h[5] = f2bf_rne(b.y); h[6] = f2bf_rne(b.z); h[7] = f2bf_rne(b.w);
    return *(short8*)h;
}
// split 8 f32 into hi (trunc bf16) + lo (RNE of residual) -- identical to all prior rounds
__device__ __forceinline__ void split8(float4 a, float4 b, short8& hi, short8& lo) {
    float v[8] = {a.x, a.y, a.z, a.w, b.x, b.y, b.z, b.w};
    ushort hh[8], ll[8];
#pragma unroll
    for (int q = 0; q < 8; q++) {
        uint u = __float_as_uint(v[q]);
        hh[q] = (ushort)(u >> 16);
        ll[q] = f2bf_rne(v[q] - __uint_as_float(u & 0xFFFF0000u));
    }
    hi = *(short8*)hh; lo = *(short8*)ll;
}

// ---------------- small utility kernels ----------------

__global__ void fill_i_kernel(int* __restrict__ p, int v, int n) {
    int i = blockIdx.x * 256 + threadIdx.x;
    if (i < n) p[i] = v;
}

__global__ void deg_kernel(const int* __restrict__ dst, int* __restrict__ deg, int E) {
    int e = blockIdx.x * 256 + threadIdx.x;
    if (e < E) atomicAdd(&deg[dst[e]], 1);
}

__global__ void rsqrt_kernel(const int* __restrict__ deg, float* __restrict__ dinv, int n) {
    int i = blockIdx.x * 256 + threadIdx.x;
    if (i < n) dinv[i] = rsqrtf((float)(deg[i] + 1));   // +1 = self-loop
}

// ---------------- 3-kernel exclusive scan ----------------

__device__ __forceinline__ int block_incl_scan(int v, int tid) {
#pragma unroll
    for (int off = 1; off < 64; off <<= 1) {
        int t = __shfl_up(v, off);
        if ((tid & 63) >= off) v += t;
    }
    __shared__ int wt[4];
    if ((tid & 63) == 63) wt[tid >> 6] = v;
    __syncthreads();
    int wid = tid >> 6;
    for (int w = 0; w < wid; w++) v += wt[w];
    __syncthreads();
    return v;
}

__global__ void scan_a_kernel(const int* __restrict__ deg, int* __restrict__ row_start,
                              int* __restrict__ blocksum, int N) {
    int tid = threadIdx.x;
    int i = blockIdx.x * 256 + tid;
    int v = (i < N) ? deg[i] : 0;
    int incl = block_incl_scan(v, tid);
    if (i < N) row_start[i + 1] = incl;
    if (tid == 255) blocksum[blockIdx.x] = incl;
}

__global__ void scan_b_kernel(int* __restrict__ blocksum, int nb) {
    int tid = threadIdx.x;
    int v = (tid < nb) ? blocksum[tid] : 0;
    int incl = block_incl_scan(v, tid);
    if (tid < nb) blocksum[tid] = incl;
}

__global__ void scan_c_kernel(int* __restrict__ row_start, int* __restrict__ cursor,
                              const int* __restrict__ blocksum, int N) {
    int b = blockIdx.x;
    int i = b * 256 + threadIdx.x;
    int add = (b > 0) ? blocksum[b - 1] : 0;
    if (i < N) {
        int v = row_start[i + 1] + add;
        row_start[i + 1] = v;
        cursor[i + 1] = v;
    }
    if (b == 0 && threadIdx.x == 0) { row_start[0] = 0; cursor[0] = 0; }
}

__global__ void scatter_kernel(const int* __restrict__ src, const int* __restrict__ dst,
                               const float* __restrict__ dinv, int* __restrict__ cursor,
                               int* __restrict__ csr_src, float* __restrict__ csr_w, int E) {
    int e = blockIdx.x * 256 + threadIdx.x;
    if (e < E) {
        int s = src[e], d = dst[e];
        int pos = atomicAdd(&cursor[d], 1);
        csr_src[pos] = s;
        csr_w[pos] = dinv[s] * dinv[d];
    }
}

// ---------------- weight prep: FRAGMENT-ORDERED layouts (r5-verified) ----------------
// Conv B: BF[n16][kq][lane][8], n16=n>>4 (16), kq=k>>5 (8), lane=((k>>3)&3)*16+(n&15), j=k&7.

__global__ void prep_bt_kernel(const float* __restrict__ B, ushort* __restrict__ BF) {
    int n = blockIdx.x, k = threadIdx.x;
    ushort v = f2bf_rne(B[k * 256 + n]);
    int lane = ((k >> 3) & 3) * 16 + (n & 15);
    int idx = ((n >> 4) * 4096) + ((k >> 5) * 512) + lane * 8 + (k & 7);
    BF[idx] = v;
}

// Gate B: rows 0..255 <- gWw, 256..511 <- gUw; hi(trunc)/lo(RNE residual) split.
__global__ void prep_gate_bt_kernel(const float* __restrict__ gWw, const float* __restrict__ gUw,
                                    ushort* __restrict__ BhF, ushort* __restrict__ BlF) {
    int n = blockIdx.x, t = threadIdx.x;
#pragma unroll
    for (int p = 0; p < 2; p++) {
        int k = p * 256 + t;
        float v = (p ? gUw : gWw)[t * 256 + n];
        uint u = __float_as_uint(v);
        ushort hi = (ushort)(u >> 16);
        ushort lo = f2bf_rne(v - __uint_as_float(u & 0xFFFF0000u));
        int lane = ((k >> 3) & 3) * 16 + (n & 15);
        int idx = ((n >> 4) * 8192) + ((k >> 5) * 512) + lane * 8 + (k & 7);
        BhF[idx] = hi; BlF[idx] = lo;
    }
}

// ---------------- HYBRID MFMA GEMM: A via dbuf LDS (1 barrier/K-step), B direct from L2 ----------------
// 64x128 block, 4 waves (2x2), wave tile 32x64.
// Per kq: issue A-loads(kq+1) -> B frag loads(kq) -> ds_read A(kq) -> 8 MFMA -> ds_write(kq+1) -> barrier.
// Barrier anchors the pipeline (r6 lesson: without it the compiler re-sinks loads to use sites).

__global__ __launch_bounds__(256, 4) void gemm_bf16_kernel(
    const float* __restrict__ A, const ushort* __restrict__ BF,
    ushort* __restrict__ C, int M)
{
    __shared__ __align__(16) ushort As[2][64 * ALD];
    const int tl = threadIdx.x;
    const int lane = tl & 63, wave = tl >> 6;
    const int wm = (wave & 1) * 32, wn = (wave >> 1) * 64;
    const int bm = blockIdx.x * 64, bn = blockIdx.y * 128;
    const int fr = lane & 15, koff = (lane >> 4) * 8;

    const int sr = tl >> 2, sc = (tl & 3) * 8;        // staging: row 0..63, col 0/8/16/24
    const bool sok = (bm + sr) < M;
    const float* sp = A + (size_t)(bm + sr) * HIDC + sc;
    const ushort* bp = BF + (size_t)((bn + wn) >> 4) * 4096 + lane * 8;

    f32x4 acc[2][4] = {};
    const float4 z4 = make_float4(0.f, 0.f, 0.f, 0.f);

    {   // prologue: stage kq=0 into buf0
        float4 u0 = sok ? *(const float4*)(sp)     : z4;
        float4 u1 = sok ? *(const float4*)(sp + 4) : z4;
        *(short8*)&As[0][sr * ALD + sc] = pack8_rne(u0, u1);
    }
    __syncthreads();

    int cur = 0;
#pragma unroll
    for (int kq = 0; kq < 8; kq++) {
        float4 n0 = z4, n1 = z4;
        if (kq + 1 < 8 && sok) {                       // 1. prefetch A(kq+1) -> regs
            n0 = *(const float4*)(sp + (kq + 1) * 32);
            n1 = *(const float4*)(sp + (kq + 1) * 32 + 4);
        }
        short8 bfv[4];                                 // 2. B frags direct (L2-resident)
#pragma unroll
        for (int nt = 0; nt < 4; nt++)
            bfv[nt] = *(const short8*)(bp + ((size_t)nt * 8 + kq) * 512);
        short8 af[2];                                  // 3. A frags from LDS
#pragma unroll
        for (int mt = 0; mt < 2; mt++)
            af[mt] = *(const short8*)&As[cur][(wm + mt * 16 + fr) * ALD + koff];
#pragma unroll
        for (int nt = 0; nt < 4; nt++) {               // 4. MFMA
            acc[0][nt] = MF(af[0], bfv[nt], acc[0][nt]);
            acc[1][nt] = MF(af[1], bfv[nt], acc[1][nt]);
        }
        if (kq + 1 < 8) {                              // 5. write next buf, 6. barrier
            *(short8*)&As[cur ^ 1][sr * ALD + sc] = pack8_rne(n0, n1);
            __syncthreads();
            cur ^= 1;
        }
    }

    // epilogue: C/D layout col=lane&15, row=(lane>>4)*4+reg  [m89-verified]
    const int row4 = (lane >> 4) * 4, coln = lane & 15;
#pragma unroll
    for (int mt = 0; mt < 2; mt++)
#pragma unroll
        for (int r = 0; r < 4; r++) {
            int m = bm + wm + mt * 16 + row4 + r;
            if (m < M) {
#pragma unroll
                for (int nt = 0; nt < 4; nt++) {
                    int n = bn + wn + nt * 16 + coln;
                    C[(size_t)m * HIDC + n] = f2bf_rne(acc[mt][nt][r]);
                }
            }
        }
}

// A already bf16 variant (conv2): staging is a pure short8 copy

__global__ __launch_bounds__(256, 4) void gemm_bf16A_kernel(
    const ushort* __restrict__ A, const ushort* __restrict__ BF,
    ushort* __restrict__ C, int M)
{
    __shared__ __align__(16) ushort As[2][64 * ALD];
    const int tl = threadIdx.x;
    const int lane = tl & 63, wave = tl >> 6;
    const int wm = (wave & 1) * 32, wn = (wave >> 1) * 64;
    const int bm = blockIdx.x * 64, bn = blockIdx.y * 128;
    const int fr = lane & 15, koff = (lane >> 4) * 8;

    const int sr = tl >> 2, sc = (tl & 3) * 8;
    const bool sok = (bm + sr) < M;
    const ushort* sp = A + (size_t)(bm + sr) * HIDC + sc;
    const ushort* bp = BF + (size_t)((bn + wn) >> 4) * 4096 + lane * 8;

    f32x4 acc[2][4] = {};
    const short8 z8 = {};

    {   // prologue
        short8 u = sok ? *(const short8*)(sp) : z8;
        *(short8*)&As[0][sr * ALD + sc] = u;
    }
    __syncthreads();

    int cur = 0;
#pragma unroll
    for (int kq = 0; kq < 8; kq++) {
        short8 nx = z8;
        if (kq + 1 < 8 && sok) nx = *(const short8*)(sp + (kq + 1) * 32);
        short8 bfv[4];
#pragma unroll
        for (int nt = 0; nt < 4; nt++)
            bfv[nt] = *(const short8*)(bp + ((size_t)nt * 8 + kq) * 512);
        short8 af[2];
#pragma unroll
        for (int mt = 0; mt < 2; mt++)
            af[mt] = *(const short8*)&As[cur][(wm + mt * 16 + fr) * ALD + koff];
#pragma unroll
        for (int nt = 0; nt < 4; nt++) {
            acc[0][nt] = MF(af[0], bfv[nt], acc[0][nt]);
            acc[1][nt] = MF(af[1], bfv[nt], acc[1][nt]);
        }
        if (kq + 1 < 8) {
            *(short8*)&As[cur ^ 1][sr * ALD + sc] = nx;
            __syncthreads();
            cur ^= 1;
        }
    }

    const int row4 = (lane >> 4) * 4, coln = lane & 15;
#pragma unroll
    for (int mt = 0; mt < 2; mt++)
#pragma unroll
        for (int r = 0; r < 4; r++) {
            int m = bm + wm + mt * 16 + row4 + r;
            if (m < M) {
#pragma unroll
                for (int nt = 0; nt < 4; nt++) {
                    int n = bn + wn + nt * 16 + coln;
                    C[(size_t)m * HIDC + n] = f2bf_rne(acc[mt][nt][r]);
                }
            }
        }
}

// ---------------- gate GEMM: hybrid, hi/lo A in dbuf LDS, B direct, fused sigmoid blend ----------------
// K=512 = concat(ht, prev); MFMA order per acc element: hh,hl,lh per ascending kq -> bit-identical.

__global__ __launch_bounds__(256, 4) void gate_kernel(
    const float* __restrict__ ht, const float* __restrict__ prev,
    const ushort* __restrict__ BhF, const ushort* __restrict__ BlF,
    const float* __restrict__ gWb, const float* __restrict__ gUb,
    float* __restrict__ out, int M)
{
    __shared__ __align__(16) ushort Ash[2][64 * ALD];
    __shared__ __align__(16) ushort Asl[2][64 * ALD];
    const int tl = threadIdx.x;
    const int lane = tl & 63, wave = tl >> 6;
    const int wm = (wave & 1) * 32, wn = (wave >> 1) * 64;
    const int bm = blockIdx.x * 64, bn = blockIdx.y * 128;
    const int fr = lane & 15, koff = (lane >> 4) * 8;

    const int sr = tl >> 2, sc = (tl & 3) * 8;
    const bool sok = (bm + sr) < M;
    const size_t sbase = (size_t)(bm + sr) * HIDC + sc;
    const ushort* bph = BhF + (size_t)((bn + wn) >> 4) * 8192 + lane * 8;
    const ushort* bpl = BlF + (size_t)((bn + wn) >> 4) * 8192 + lane * 8;

    f32x4 acc[2][4] = {};
    const float4 z4 = make_float4(0.f, 0.f, 0.f, 0.f);

    {   // prologue: stage kq=0 (from ht)
        float4 u0 = sok ? *(const float4*)(ht + sbase)     : z4;
        float4 u1 = sok ? *(const float4*)(ht + sbase + 4) : z4;
        short8 hi, lo; split8(u0, u1, hi, lo);
        *(short8*)&Ash[0][sr * ALD + sc] = hi;
        *(short8*)&Asl[0][sr * ALD + sc] = lo;
    }
    __syncthreads();

    int cur = 0;
#pragma unroll
    for (int kq = 0; kq < 16; kq++) {
        float4 n0 = z4, n1 = z4;
        if (kq + 1 < 16 && sok) {                      // 1. prefetch A(kq+1)
            const float* S = ((kq + 1) < 8) ? ht : prev;
            const int cb = ((kq + 1) & 7) * 32;
            n0 = *(const float4*)(S + sbase + cb);
            n1 = *(const float4*)(S + sbase + cb + 4);
        }
        short8 bh[4], bl[4];                           // 2. B frags direct
#pragma unroll
        for (int nt = 0; nt < 4; nt++) {
            size_t off = ((size_t)nt * 16 + kq) * 512;
            bh[nt] = *(const short8*)(bph + off);
            bl[nt] = *(const short8*)(bpl + off);
        }
        short8 ah[2], al[2];                           // 3. A frags from LDS
#pragma unroll
        for (int mt = 0; mt < 2; mt++) {
            ah[mt] = *(const short8*)&Ash[cur][(wm + mt * 16 + fr) * ALD + koff];
            al[mt] = *(const short8*)&Asl[cur][(wm + mt * 16 + fr) * ALD + koff];
        }
#pragma unroll
        for (int nt = 0; nt < 4; nt++) {               // 4. MFMA (hh, hl, lh)
            acc[0][nt] = MF(ah[0], bh[nt], acc[0][nt]);
            acc[0][nt] = MF(ah[0], bl[nt], acc[0][nt]);
            acc[0][nt] = MF(al[0], bh[nt], acc[0][nt]);
            acc[1][nt] = MF(ah[1], bh[nt], acc[1][nt]);
            acc[1][nt] = MF(ah[1], bl[nt], acc[1][nt]);
            acc[1][nt] = MF(al[1], bh[nt], acc[1][nt]);
        }
        if (kq + 1 < 16) {                             // 5.+6. write next buf, barrier
            short8 hi, lo; split8(n0, n1, hi, lo);
            *(short8*)&Ash[cur ^ 1][sr * ALD + sc] = hi;
            *(short8*)&Asl[cur ^ 1][sr * ALD + sc] = lo;
            __syncthreads();
            cur ^= 1;
        }
    }

    const int row4 = (lane >> 4) * 4, coln = lane & 15;
#pragma unroll
    for (int mt = 0; mt < 2; mt++)
#pragma unroll
        for (int r = 0; r < 4; r++) {
            int m = bm + wm + mt * 16 + row4 + r;
            if (m < M) {
#pragma unroll
                for (int nt = 0; nt < 4; nt++) {
                    int n = bn + wn + nt * 16 + coln;
                    size_t idx = (size_t)m * HIDC + n;
                    float g = acc[mt][nt][r] + gWb[n] + gUb[n];
                    float alpha = 1.f / (1.f + expf(-g));
                    out[idx] = alpha * ht[idx] + (1.f - alpha) * prev[idx];
                }
            }
        }
}

// ---------------- CSR aggregation: one WAVE per row, ushort4 gathers, 4-deep unroll ----------------

__global__ __launch_bounds__(256) void csr_agg_kernel(
    const ushort* __restrict__ hm, const int* __restrict__ row_start,
    const int* __restrict__ csr_src, const float* __restrict__ csr_w,
    const float* __restrict__ dinv, const float* __restrict__ bias,
    float* __restrict__ outf, ushort* __restrict__ outb, int do_relu, int N)
{
    const int wave = threadIdx.x >> 6, lane = threadIdx.x & 63;
    const int i = blockIdx.x * 4 + wave;
    if (i >= N) return;
    const int c = lane * 4;

    const float di = dinv[i];
    const float s2 = di * di;
    ushort4 sv = *(const ushort4*)(hm + (size_t)i * HIDC + c);
    float a0 = s2 * bf2f(sv.x), a1 = s2 * bf2f(sv.y);
    float a2 = s2 * bf2f(sv.z), a3 = s2 * bf2f(sv.w);

    const int b0 = row_start[i], b1 = row_start[i + 1];
    int t = b0;
    for (; t + 4 <= b1; t += 4) {
        int   i0 = csr_src[t],     i1 = csr_src[t + 1];
        int   i2 = csr_src[t + 2], i3 = csr_src[t + 3];
        float w0 = csr_w[t],       w1 = csr_w[t + 1];
        float w2 = csr_w[t + 2],   w3 = csr_w[t + 3];
        ushort4 v0 = *(const ushort4*)(hm + (size_t)i0 * HIDC + c);
        ushort4 v1 = *(const ushort4*)(hm + (size_t)i1 * HIDC + c);
        ushort4 v2 = *(const ushort4*)(hm + (size_t)i2 * HIDC + c);
        ushort4 v3 = *(const ushort4*)(hm + (size_t)i3 * HIDC + c);
        a0 += w0 * bf2f(v0.x); a1 += w0 * bf2f(v0.y); a2 += w0 * bf2f(v0.z); a3 += w0 * bf2f(v0.w);
        a0 += w1 * bf2f(v1.x); a1 += w1 * bf2f(v1.y); a2 += w1 * bf2f(v1.z); a3 += w1 * bf2f(v1.w);
        a0 += w2 * bf2f(v2.x); a1 += w2 * bf2f(v2.y); a2 += w2 * bf2f(v2.z); a3 += w2 * bf2f(v2.w);
        a0 += w3 * bf2f(v3.x); a1 += w3 * bf2f(v3.y); a2 += w3 * bf2f(v3.z); a3 += w3 * bf2f(v3.w);
    }
    for (; t < b1; ++t) {
        int s_ = csr_src[t];
        float w = csr_w[t];
        ushort4 v = *(const ushort4*)(hm + (size_t)s_ * HIDC + c);
        a0 += w * bf2f(v.x); a1 += w * bf2f(v.y); a2 += w * bf2f(v.z); a3 += w * bf2f(v.w);
    }

    float4 bb = *(const float4*)(bias + c);
    a0 += bb.x; a1 += bb.y; a2 += bb.z; a3 += bb.w;
    if (do_relu) {
        a0 = fmaxf(a0, 0.f); a1 = fmaxf(a1, 0.f);
        a2 = fmaxf(a2, 0.f); a3 = fmaxf(a3, 0.f);
    }
    if (outb) {
        ushort4 o;
        o.x = f2bf_rne(a0); o.y = f2bf_rne(a1);
        o.z = f2bf_rne(a2); o.w = f2bf_rne(a3);
        *(ushort4*)(outb + (size_t)i * HIDC + c) = o;
    } else {
        *(float4*)(outf + (size_t)i * HIDC + c) = make_float4(a0, a1, a2, a3);
    }
}

// ---------------- launch ----------------

extern "C" void kernel_launch(void* const* d_in, const int* in_sizes, int n_in,
                              void* d_out, int out_size, void* d_ws, size_t ws_size,
                              hipStream_t stream) {
    const float* x    = (const float*)d_in[0];
    const int*   ei   = (const int*)d_in[1];
    const float* prev = (const float*)d_in[2];
    const float* W1   = (const float*)d_in[3];
    const float* b1   = (const float*)d_in[4];
    const float* W2   = (const float*)d_in[5];
    const float* b2   = (const float*)d_in[6];
    const float* gWw  = (const float*)d_in[7];
    const float* gWb  = (const float*)d_in[8];
    const float* gUw  = (const float*)d_in[9];
    const float* gUb  = (const float*)d_in[10];

    const int N = in_sizes[0] / HIDC;
    const int E = in_sizes[1] / 2;
    const int* src = ei;
    const int* dst = ei + E;

    float* out  = (float*)d_out;
    float* out1 = out;                       // h_tilde region (scratch first: h bf16)
    float* ht   = out + (size_t)N * HIDC;    // h_t region (f32)
    ushort* hbf = (ushort*)out1;             // bf16 h lives in out1 region until gate overwrites it

    // workspace layout (float units, 64-aligned chunks)
    float* ws = (float*)d_ws;
    size_t o = 0;
    auto take = [&](size_t n) { size_t r = o; o += (n + 63) & ~(size_t)63; return r; };
    float*  dinv    = ws + take(N);
    int*    degi    = (int*)(ws + take(N));
    int*    row_st  = (int*)(ws + take(N + 1));
    int*    cursor  = (int*)(ws + take(N + 1));
    int*    csr_src = (int*)(ws + take(E));
    float*  csr_w   = ws + take(E);
    ushort* Bt1F    = (ushort*)(ws + take(256 * 256 / 2));
    ushort* Bt2F    = (ushort*)(ws + take(256 * 256 / 2));
    ushort* BthF    = (ushort*)(ws + take(256 * 512 / 2));
    ushort* BtlF    = (ushort*)(ws + take(256 * 512 / 2));
    ushort* hm      = (ushort*)(ws + take((size_t)N * HIDC / 2));

    const int nbN = (N + 255) / 256;
    const int nbE = (E + 255) / 256;
    dim3 ggrid((N + 63) / 64, 2);
    const int nbAgg = (N + 3) / 4;

    // ---- CSR build ----
    int* blocksum = (int*)csr_w;  // free until scatter_kernel
    fill_i_kernel<<<nbN, 256, 0, stream>>>(degi, 0, N);
    deg_kernel<<<nbE, 256, 0, stream>>>(dst, degi, E);
    scan_a_kernel<<<nbN, 256, 0, stream>>>(degi, row_st, blocksum, N);
    scan_b_kernel<<<1, 256, 0, stream>>>(blocksum, nbN);
    scan_c_kernel<<<nbN, 256, 0, stream>>>(row_st, cursor, blocksum, N);
    rsqrt_kernel<<<nbN, 256, 0, stream>>>(degi, dinv, N);
    scatter_kernel<<<nbE, 256, 0, stream>>>(src, dst, dinv, cursor, csr_src, csr_w, E);

    // ---- weight prep (fragment-ordered) ----
    prep_bt_kernel<<<256, 256, 0, stream>>>(W1, Bt1F);
    prep_bt_kernel<<<256, 256, 0, stream>>>(W2, Bt2F);
    prep_gate_bt_kernel<<<256, 256, 0, stream>>>(gWw, gUw, BthF, BtlF);

    // ---- conv1 ----
    gemm_bf16_kernel<<<ggrid, 256, 0, stream>>>(x, Bt1F, hm, N);
    csr_agg_kernel<<<nbAgg, 256, 0, stream>>>(hm, row_st, csr_src, csr_w, dinv, b1,
                                              nullptr, hbf, 1, N);

    // ---- conv2 (A already bf16) ----
    gemm_bf16A_kernel<<<ggrid, 256, 0, stream>>>(hbf, Bt2F, hm, N);
    csr_agg_kernel<<<nbAgg, 256, 0, stream>>>(hm, row_st, csr_src, csr_w, dinv, b2,
                                              ht, nullptr, 0, N);

    // ---- gate (fused final; overwrites hbf region, which is fully consumed) ----
    gate_kernel<<<ggrid, 256, 0, stream>>>(ht, prev, BthF, BtlF, gWb, gUb, out1, N);

    (void)n_in; (void)out_size; (void)ws_size;
}

// Round 10
// 509.158 us; speedup vs baseline: 1.1143x; 1.0279x over previous
//
#include <hip/hip_runtime.h>
#include <hip/hip_bf16.h>
#include <math.h>

#define HIDC 256
#define LSTR 40   // LDS row stride in ushorts: 80 B = 16B-aligned; stride=20 banks -> ~2-way (free per m136).

typedef short short8 __attribute__((ext_vector_type(8)));
typedef float f32x4 __attribute__((ext_vector_type(4)));

__device__ __forceinline__ ushort f2bf_rne(float f) {
    uint u = __float_as_uint(f);
    u += 0x7FFF + ((u >> 16) & 1);
    return (ushort)(u >> 16);
}
__device__ __forceinline__ float bf2f(ushort h) {
    return __uint_as_float(((uint)h) << 16);
}

// ---------------- small utility kernels ----------------

__global__ void fill_i_kernel(int* __restrict__ p, int v, int n) {
    int i = blockIdx.x * 256 + threadIdx.x;
    if (i < n) p[i] = v;
}

__global__ void deg_kernel(const int* __restrict__ dst, int* __restrict__ deg, int E) {
    int e = blockIdx.x * 256 + threadIdx.x;
    if (e < E) atomicAdd(&deg[dst[e]], 1);
}

__global__ void rsqrt_kernel(const int* __restrict__ deg, float* __restrict__ dinv, int n) {
    int i = blockIdx.x * 256 + threadIdx.x;
    if (i < n) dinv[i] = rsqrtf((float)(deg[i] + 1));   // +1 = self-loop
}

// ---------------- 3-kernel exclusive scan ----------------

__device__ __forceinline__ int block_incl_scan(int v, int tid) {
#pragma unroll
    for (int off = 1; off < 64; off <<= 1) {
        int t = __shfl_up(v, off);
        if ((tid & 63) >= off) v += t;
    }
    __shared__ int wt[4];
    if ((tid & 63) == 63) wt[tid >> 6] = v;
    __syncthreads();
    int wid = tid >> 6;
    for (int w = 0; w < wid; w++) v += wt[w];
    __syncthreads();
    return v;
}

__global__ void scan_a_kernel(const int* __restrict__ deg, int* __restrict__ row_start,
                              int* __restrict__ blocksum, int N) {
    int tid = threadIdx.x;
    int i = blockIdx.x * 256 + tid;
    int v = (i < N) ? deg[i] : 0;
    int incl = block_incl_scan(v, tid);
    if (i < N) row_start[i + 1] = incl;
    if (tid == 255) blocksum[blockIdx.x] = incl;
}

__global__ void scan_b_kernel(int* __restrict__ blocksum, int nb) {
    int tid = threadIdx.x;
    int v = (tid < nb) ? blocksum[tid] : 0;
    int incl = block_incl_scan(v, tid);
    if (tid < nb) blocksum[tid] = incl;
}

__global__ void scan_c_kernel(int* __restrict__ row_start, int* __restrict__ cursor,
                              const int* __restrict__ blocksum, int N) {
    int b = blockIdx.x;
    int i = b * 256 + threadIdx.x;
    int add = (b > 0) ? blocksum[b - 1] : 0;
    if (i < N) {
        int v = row_start[i + 1] + add;
        row_start[i + 1] = v;
        cursor[i + 1] = v;
    }
    if (b == 0 && threadIdx.x == 0) { row_start[0] = 0; cursor[0] = 0; }
}

__global__ void scatter_kernel(const int* __restrict__ src, const int* __restrict__ dst,
                               const float* __restrict__ dinv, int* __restrict__ cursor,
                               int* __restrict__ csr_src, float* __restrict__ csr_w, int E) {
    int e = blockIdx.x * 256 + threadIdx.x;
    if (e < E) {
        int s = src[e], d = dst[e];
        int pos = atomicAdd(&cursor[d], 1);
        csr_src[pos] = s;
        csr_w[pos] = dinv[s] * dinv[d];
    }
}

// ---------------- weight prep: Bt[n][k] = bf16(B[k][n]) ----------------

__global__ void prep_bt_kernel(const float* __restrict__ B, ushort* __restrict__ Bt) {
    int n = blockIdx.x, k = threadIdx.x;
    Bt[n * 256 + k] = f2bf_rne(B[k * 256 + n]);
}

// combined gate weights: rows 0..255 <- gWw, 256..511 <- gUw, hi/lo split, [n][512k]
__global__ void prep_gate_bt_kernel(const float* __restrict__ gWw, const float* __restrict__ gUw,
                                    ushort* __restrict__ Bth, ushort* __restrict__ Btl) {
    int n = blockIdx.x, k = threadIdx.x;
    float v1 = gWw[k * 256 + n];
    uint u1 = __float_as_uint(v1);
    Bth[n * 512 + k] = (ushort)(u1 >> 16);
    Btl[n * 512 + k] = f2bf_rne(v1 - __uint_as_float(u1 & 0xFFFF0000u));
    float v2 = gUw[k * 256 + n];
    uint u2 = __float_as_uint(v2);
    Bth[n * 512 + 256 + k] = (ushort)(u2 >> 16);
    Btl[n * 512 + 256 + k] = f2bf_rne(v2 - __uint_as_float(u2 & 0xFFFF0000u));
}

// ---------------- MFMA GEMM (r2-measured-best conv form): 128x128 tile, staged A+B ----------------

__global__ __launch_bounds__(256, 4) void gemm_bf16_kernel(
    const float* __restrict__ A, const ushort* __restrict__ Bt,  // Bt: [256n][256k] bf16
    ushort* __restrict__ C, int M)
{
    __shared__ __align__(16) ushort As[128 * LSTR];
    __shared__ __align__(16) ushort Bs[128 * LSTR];
    const int tl = threadIdx.x;
    const int lane = tl & 63, wave = tl >> 6;
    const int wm = (wave & 1) * 64, wn = (wave >> 1) * 64;
    const int bm = blockIdx.x * 128, bn = blockIdx.y * 128;

    const int ar  = tl >> 1;          // A stage row
    const int akq = (tl & 1) * 16;    // A stage k base (16 floats)
    const bool aok = (bm + ar) < M;

    f32x4 acc[4][4] = {};

    for (int k0 = 0; k0 < 256; k0 += 32) {
        {   // A stage: f32 -> bf16 RNE
            const float* ap = A + (size_t)(bm + ar) * HIDC + k0 + akq;
#pragma unroll
            for (int j = 0; j < 4; j++) {
                float4 v = aok ? *(const float4*)(ap + 4 * j) : make_float4(0.f, 0.f, 0.f, 0.f);
                ushort4 h;
                h.x = f2bf_rne(v.x); h.y = f2bf_rne(v.y);
                h.z = f2bf_rne(v.z); h.w = f2bf_rne(v.w);
                *(ushort4*)&As[ar * LSTR + akq + 4 * j] = h;
            }
        }
        {   // B stage: copy 32 B
            const ushort* bp = Bt + (size_t)(bn + ar) * 256 + k0 + akq;
            *(uint4*)&Bs[ar * LSTR + akq]     = *(const uint4*)bp;
            *(uint4*)&Bs[ar * LSTR + akq + 8] = *(const uint4*)(bp + 8);
        }
        __syncthreads();
        const int fr = lane & 15, koff = (lane >> 4) * 8;
        short8 af[4], bfv[4];
#pragma unroll
        for (int t = 0; t < 4; t++) {
            af[t]  = *(const short8*)&As[(wm + t * 16 + fr) * LSTR + koff];
            bfv[t] = *(const short8*)&Bs[(wn + t * 16 + fr) * LSTR + koff];
        }
#pragma unroll
        for (int mt = 0; mt < 4; mt++)
#pragma unroll
            for (int nt = 0; nt < 4; nt++)
                acc[mt][nt] = __builtin_amdgcn_mfma_f32_16x16x32_bf16(af[mt], bfv[nt], acc[mt][nt], 0, 0, 0);
        __syncthreads();
    }

    // epilogue: C/D layout col=lane&15, row=(lane>>4)*4+reg  [m89-verified]
    const int row4 = (lane >> 4) * 4, coln = lane & 15;
#pragma unroll
    for (int mt = 0; mt < 4; mt++)
#pragma unroll
        for (int r = 0; r < 4; r++) {
            int m = bm + wm + mt * 16 + row4 + r;
            if (m < M) {
#pragma unroll
                for (int nt = 0; nt < 4; nt++) {
                    int n = bn + wn + nt * 16 + coln;
                    C[(size_t)m * HIDC + n] = f2bf_rne(acc[mt][nt][r]);
                }
            }
        }
}

// ---------------- MFMA GEMM, A already bf16 (pure-copy staging), r2 form ----------------

__global__ __launch_bounds__(256, 4) void gemm_bf16A_kernel(
    const ushort* __restrict__ A, const ushort* __restrict__ Bt,  // A: [M][256] bf16
    ushort* __restrict__ C, int M)
{
    __shared__ __align__(16) ushort As[128 * LSTR];
    __shared__ __align__(16) ushort Bs[128 * LSTR];
    const int tl = threadIdx.x;
    const int lane = tl & 63, wave = tl >> 6;
    const int wm = (wave & 1) * 64, wn = (wave >> 1) * 64;
    const int bm = blockIdx.x * 128, bn = blockIdx.y * 128;

    const int ar  = tl >> 1;
    const int akq = (tl & 1) * 16;
    const bool aok = (bm + ar) < M;

    f32x4 acc[4][4] = {};

    for (int k0 = 0; k0 < 256; k0 += 32) {
        {   // A stage: pure 16-ushort copy
            const ushort* ap = A + (size_t)(bm + ar) * HIDC + k0 + akq;
            uint4 z = make_uint4(0u, 0u, 0u, 0u);
            *(uint4*)&As[ar * LSTR + akq]     = aok ? *(const uint4*)ap       : z;
            *(uint4*)&As[ar * LSTR + akq + 8] = aok ? *(const uint4*)(ap + 8) : z;
        }
        {   // B stage
            const ushort* bp = Bt + (size_t)(bn + ar) * 256 + k0 + akq;
            *(uint4*)&Bs[ar * LSTR + akq]     = *(const uint4*)bp;
            *(uint4*)&Bs[ar * LSTR + akq + 8] = *(const uint4*)(bp + 8);
        }
        __syncthreads();
        const int fr = lane & 15, koff = (lane >> 4) * 8;
        short8 af[4], bfv[4];
#pragma unroll
        for (int t = 0; t < 4; t++) {
            af[t]  = *(const short8*)&As[(wm + t * 16 + fr) * LSTR + koff];
            bfv[t] = *(const short8*)&Bs[(wn + t * 16 + fr) * LSTR + koff];
        }
#pragma unroll
        for (int mt = 0; mt < 4; mt++)
#pragma unroll
            for (int nt = 0; nt < 4; nt++)
                acc[mt][nt] = __builtin_amdgcn_mfma_f32_16x16x32_bf16(af[mt], bfv[nt], acc[mt][nt], 0, 0, 0);
        __syncthreads();
    }

    const int row4 = (lane >> 4) * 4, coln = lane & 15;
#pragma unroll
    for (int mt = 0; mt < 4; mt++)
#pragma unroll
        for (int r = 0; r < 4; r++) {
            int m = bm + wm + mt * 16 + row4 + r;
            if (m < M) {
#pragma unroll
                for (int nt = 0; nt < 4; nt++) {
                    int n = bn + wn + nt * 16 + coln;
                    C[(size_t)m * HIDC + n] = f2bf_rne(acc[mt][nt][r]);
                }
            }
        }
}

// ---------------- gate GEMM (r4-measured-best form): BM=64, staged hi/lo A + hi/lo B ----------------

__global__ __launch_bounds__(256, 4) void gate_kernel(
    const float* __restrict__ ht, const float* __restrict__ prev,
    const ushort* __restrict__ Bth, const ushort* __restrict__ Btl,  // [256n][512k]
    const float* __restrict__ gWb, const float* __restrict__ gUb,
    float* __restrict__ out, int M)
{
    __shared__ __align__(16) ushort Ash[64 * LSTR];
    __shared__ __align__(16) ushort Asl[64 * LSTR];
    __shared__ __align__(16) ushort Bsh[128 * LSTR];
    __shared__ __align__(16) ushort Bsl[128 * LSTR];
    const int tl = threadIdx.x;
    const int lane = tl & 63, wave = tl >> 6;
    const int wm = (wave & 1) * 32, wn = (wave >> 1) * 64;
    const int bm = blockIdx.x * 64, bn = blockIdx.y * 128;

    const int arA = tl >> 2;          // 0..63
    const int kqA = (tl & 3) * 8;     // 8 floats
    const int arB = tl >> 1;
    const int kqB = (tl & 1) * 16;
    const bool aok = (bm + arA) < M;

    f32x4 acc[2][4] = {};

    for (int k0 = 0; k0 < 512; k0 += 32) {
        {   // A stage: hi/lo split from ht (k<256) or prev, 8 elems/thread
            const float* srcA = (k0 < 256) ? ht : prev;
            const float* ap = srcA + (size_t)(bm + arA) * HIDC + (k0 & 255) + kqA;
            float4 v0 = aok ? *(const float4*)(ap)     : make_float4(0.f, 0.f, 0.f, 0.f);
            float4 v1 = aok ? *(const float4*)(ap + 4) : make_float4(0.f, 0.f, 0.f, 0.f);
            float vv[8] = {v0.x, v0.y, v0.z, v0.w, v1.x, v1.y, v1.z, v1.w};
            ushort hp[8], lp[8];
#pragma unroll
            for (int q = 0; q < 8; q++) {
                uint u = __float_as_uint(vv[q]);
                hp[q] = (ushort)(u >> 16);
                lp[q] = f2bf_rne(vv[q] - __uint_as_float(u & 0xFFFF0000u));
            }
            *(ushort4*)&Ash[arA * LSTR + kqA]     = make_ushort4(hp[0], hp[1], hp[2], hp[3]);
            *(ushort4*)&Ash[arA * LSTR + kqA + 4] = make_ushort4(hp[4], hp[5], hp[6], hp[7]);
            *(ushort4*)&Asl[arA * LSTR + kqA]     = make_ushort4(lp[0], lp[1], lp[2], lp[3]);
            *(ushort4*)&Asl[arA * LSTR + kqA + 4] = make_ushort4(lp[4], lp[5], lp[6], lp[7]);
        }
        {   // B stage
            const ushort* bph = Bth + (size_t)(bn + arB) * 512 + k0 + kqB;
            const ushort* bpl = Btl + (size_t)(bn + arB) * 512 + k0 + kqB;
            *(uint4*)&Bsh[arB * LSTR + kqB]     = *(const uint4*)bph;
            *(uint4*)&Bsh[arB * LSTR + kqB + 8] = *(const uint4*)(bph + 8);
            *(uint4*)&Bsl[arB * LSTR + kqB]     = *(const uint4*)bpl;
            *(uint4*)&Bsl[arB * LSTR + kqB + 8] = *(const uint4*)(bpl + 8);
        }
        __syncthreads();
        const int fr = lane & 15, koff = (lane >> 4) * 8;
        short8 afh[2], afl[2], bfh[4], bfl[4];
#pragma unroll
        for (int t = 0; t < 2; t++) {
            afh[t] = *(const short8*)&Ash[(wm + t * 16 + fr) * LSTR + koff];
            afl[t] = *(const short8*)&Asl[(wm + t * 16 + fr) * LSTR + koff];
        }
#pragma unroll
        for (int t = 0; t < 4; t++) {
            bfh[t] = *(const short8*)&Bsh[(wn + t * 16 + fr) * LSTR + koff];
            bfl[t] = *(const short8*)&Bsl[(wn + t * 16 + fr) * LSTR + koff];
        }
#pragma unroll
        for (int mt = 0; mt < 2; mt++)
#pragma unroll
            for (int nt = 0; nt < 4; nt++) {
                acc[mt][nt] = __builtin_amdgcn_mfma_f32_16x16x32_bf16(afh[mt], bfh[nt], acc[mt][nt], 0, 0, 0);
                acc[mt][nt] = __builtin_amdgcn_mfma_f32_16x16x32_bf16(afh[mt], bfl[nt], acc[mt][nt], 0, 0, 0);
                acc[mt][nt] = __builtin_amdgcn_mfma_f32_16x16x32_bf16(afl[mt], bfh[nt], acc[mt][nt], 0, 0, 0);
            }
        __syncthreads();
    }

    const int row4 = (lane >> 4) * 4, coln = lane & 15;
#pragma unroll
    for (int mt = 0; mt < 2; mt++)
#pragma unroll
        for (int r = 0; r < 4; r++) {
            int m = bm + wm + mt * 16 + row4 + r;
            if (m < M) {
#pragma unroll
                for (int nt = 0; nt < 4; nt++) {
                    int n = bn + wn + nt * 16 + coln;
                    size_t idx = (size_t)m * HIDC + n;
                    float g = acc[mt][nt][r] + gWb[n] + gUb[n];
                    float alpha = 1.f / (1.f + expf(-g));
                    out[idx] = alpha * ht[idx] + (1.f - alpha) * prev[idx];
                }
            }
        }
}

// ---------------- CSR aggregation: one WAVE per row, ushort4 gathers, 4-deep unroll ----------------

__global__ __launch_bounds__(256) void csr_agg_kernel(
    const ushort* __restrict__ hm, const int* __restrict__ row_start,
    const int* __restrict__ csr_src, const float* __restrict__ csr_w,
    const float* __restrict__ dinv, const float* __restrict__ bias,
    float* __restrict__ outf, ushort* __restrict__ outb, int do_relu, int N)
{
    const int wave = threadIdx.x >> 6, lane = threadIdx.x & 63;
    const int i = blockIdx.x * 4 + wave;
    if (i >= N) return;
    const int c = lane * 4;

    const float di = dinv[i];
    const float s2 = di * di;
    ushort4 sv = *(const ushort4*)(hm + (size_t)i * HIDC + c);
    float a0 = s2 * bf2f(sv.x), a1 = s2 * bf2f(sv.y);
    float a2 = s2 * bf2f(sv.z), a3 = s2 * bf2f(sv.w);

    const int b0 = row_start[i], b1 = row_start[i + 1];
    int t = b0;
    for (; t + 4 <= b1; t += 4) {
        int   i0 = csr_src[t],     i1 = csr_src[t + 1];
        int   i2 = csr_src[t + 2], i3 = csr_src[t + 3];
        float w0 = csr_w[t],       w1 = csr_w[t + 1];
        float w2 = csr_w[t + 2],   w3 = csr_w[t + 3];
        ushort4 v0 = *(const ushort4*)(hm + (size_t)i0 * HIDC + c);
        ushort4 v1 = *(const ushort4*)(hm + (size_t)i1 * HIDC + c);
        ushort4 v2 = *(const ushort4*)(hm + (size_t)i2 * HIDC + c);
        ushort4 v3 = *(const ushort4*)(hm + (size_t)i3 * HIDC + c);
        a0 += w0 * bf2f(v0.x); a1 += w0 * bf2f(v0.y); a2 += w0 * bf2f(v0.z); a3 += w0 * bf2f(v0.w);
        a0 += w1 * bf2f(v1.x); a1 += w1 * bf2f(v1.y); a2 += w1 * bf2f(v1.z); a3 += w1 * bf2f(v1.w);
        a0 += w2 * bf2f(v2.x); a1 += w2 * bf2f(v2.y); a2 += w2 * bf2f(v2.z); a3 += w2 * bf2f(v2.w);
        a0 += w3 * bf2f(v3.x); a1 += w3 * bf2f(v3.y); a2 += w3 * bf2f(v3.z); a3 += w3 * bf2f(v3.w);
    }
    for (; t < b1; ++t) {
        int s_ = csr_src[t];
        float w = csr_w[t];
        ushort4 v = *(const ushort4*)(hm + (size_t)s_ * HIDC + c);
        a0 += w * bf2f(v.x); a1 += w * bf2f(v.y); a2 += w * bf2f(v.z); a3 += w * bf2f(v.w);
    }

    float4 bb = *(const float4*)(bias + c);
    a0 += bb.x; a1 += bb.y; a2 += bb.z; a3 += bb.w;
    if (do_relu) {
        a0 = fmaxf(a0, 0.f); a1 = fmaxf(a1, 0.f);
        a2 = fmaxf(a2, 0.f); a3 = fmaxf(a3, 0.f);
    }
    if (outb) {
        ushort4 o;
        o.x = f2bf_rne(a0); o.y = f2bf_rne(a1);
        o.z = f2bf_rne(a2); o.w = f2bf_rne(a3);
        *(ushort4*)(outb + (size_t)i * HIDC + c) = o;
    } else {
        *(float4*)(outf + (size_t)i * HIDC + c) = make_float4(a0, a1, a2, a3);
    }
}

// ---------------- launch ----------------

extern "C" void kernel_launch(void* const* d_in, const int* in_sizes, int n_in,
                              void* d_out, int out_size, void* d_ws, size_t ws_size,
                              hipStream_t stream) {
    const float* x    = (const float*)d_in[0];
    const int*   ei   = (const int*)d_in[1];
    const float* prev = (const float*)d_in[2];
    const float* W1   = (const float*)d_in[3];
    const float* b1   = (const float*)d_in[4];
    const float* W2   = (const float*)d_in[5];
    const float* b2   = (const float*)d_in[6];
    const float* gWw  = (const float*)d_in[7];
    const float* gWb  = (const float*)d_in[8];
    const float* gUw  = (const float*)d_in[9];
    const float* gUb  = (const float*)d_in[10];

    const int N = in_sizes[0] / HIDC;
    const int E = in_sizes[1] / 2;
    const int* src = ei;
    const int* dst = ei + E;

    float* out  = (float*)d_out;
    float* out1 = out;                       // h_tilde region (scratch first: h bf16)
    float* ht   = out + (size_t)N * HIDC;    // h_t region (f32)
    ushort* hbf = (ushort*)out1;             // bf16 h lives in out1 region until gate overwrites it

    // workspace layout (float units, 64-aligned chunks)
    float* ws = (float*)d_ws;
    size_t o = 0;
    auto take = [&](size_t n) { size_t r = o; o += (n + 63) & ~(size_t)63; return r; };
    float*  dinv    = ws + take(N);
    int*    degi    = (int*)(ws + take(N));
    int*    row_st  = (int*)(ws + take(N + 1));
    int*    cursor  = (int*)(ws + take(N + 1));
    int*    csr_src = (int*)(ws + take(E));
    float*  csr_w   = ws + take(E);
    ushort* Bt1     = (ushort*)(ws + take(256 * 256 / 2));
    ushort* Bt2     = (ushort*)(ws + take(256 * 256 / 2));
    ushort* Bth     = (ushort*)(ws + take(256 * 512 / 2));
    ushort* Btl     = (ushort*)(ws + take(256 * 512 / 2));
    ushort* hm      = (ushort*)(ws + take((size_t)N * HIDC / 2));

    const int nbN = (N + 255) / 256;
    const int nbE = (E + 255) / 256;
    dim3 ggrid((N + 127) / 128, 2);    // convs: BM=128 (r2-best)
    dim3 ggridG((N + 63) / 64, 2);     // gate:  BM=64  (r4-best)
    const int nbAgg = (N + 3) / 4;

    // ---- CSR build ----
    int* blocksum = (int*)csr_w;  // free until scatter_kernel
    fill_i_kernel<<<nbN, 256, 0, stream>>>(degi, 0, N);
    deg_kernel<<<nbE, 256, 0, stream>>>(dst, degi, E);
    scan_a_kernel<<<nbN, 256, 0, stream>>>(degi, row_st, blocksum, N);
    scan_b_kernel<<<1, 256, 0, stream>>>(blocksum, nbN);
    scan_c_kernel<<<nbN, 256, 0, stream>>>(row_st, cursor, blocksum, N);
    rsqrt_kernel<<<nbN, 256, 0, stream>>>(degi, dinv, N);
    scatter_kernel<<<nbE, 256, 0, stream>>>(src, dst, dinv, cursor, csr_src, csr_w, E);

    // ---- weight prep ----
    prep_bt_kernel<<<256, 256, 0, stream>>>(W1, Bt1);
    prep_bt_kernel<<<256, 256, 0, stream>>>(W2, Bt2);
    prep_gate_bt_kernel<<<256, 256, 0, stream>>>(gWw, gUw, Bth, Btl);

    // ---- conv1 ----
    gemm_bf16_kernel<<<ggrid, 256, 0, stream>>>(x, Bt1, hm, N);
    csr_agg_kernel<<<nbAgg, 256, 0, stream>>>(hm, row_st, csr_src, csr_w, dinv, b1,
                                              nullptr, hbf, 1, N);

    // ---- conv2 (A already bf16) ----
    gemm_bf16A_kernel<<<ggrid, 256, 0, stream>>>(hbf, Bt2, hm, N);
    csr_agg_kernel<<<nbAgg, 256, 0, stream>>>(hm, row_st, csr_src, csr_w, dinv, b2,
                                              ht, nullptr, 0, N);

    // ---- gate (fused final; overwrites hbf region, which is fully consumed) ----
    gate_kernel<<<ggridG, 256, 0, stream>>>(ht, prev, Bth, Btl, gWb, gUb, out1, N);

    (void)n_in; (void)out_size; (void)ws_size;
}